// Round 5
// baseline (401.854 us; speedup 1.0000x reference)
//
#include <hip/hip_runtime.h>

// RNN: B=4096, T=512, I=15, H=64, O=1
// R4: 512-thread blocks (8 waves), block owns 16 batches; wave w owns j in
// [8w, 8w+8) inside a 16-wide MFMA tile (cols n>=8 of W are zero-padded).
// 256 blocks x 8 waves = 2048 waves = 2 waves/SIMD (was 1) -> stall hiding.
// Cost: 2x MFMA + 2x epilogue issue per SIMD (MfmaUtil was only 10%).
// LDS: 256B row stride + XOR-chunk swizzle (chunk^ (row&7)) -> min-phase
// conflict-free b128; h written once (q<2 lanes), hi+lo compensation kept.
// Raw s_barrier (lgkmcnt only) so x prefetch loads stay in flight.

#define T_STEPS 512
#define I_DIM 15
#define BPB 16            // batches per block
#define ROWSH 128         // LDS row stride in shorts (16 chunks x 8 shorts)
#define DPF 8             // x prefetch depth

typedef __attribute__((ext_vector_type(8))) short short8;
typedef __attribute__((ext_vector_type(4))) float float4v;

__device__ __forceinline__ short f2bf_rne(float f) {
    union { float f; unsigned u; } v; v.f = f;
    unsigned r = (v.u + 0x7FFFu + ((v.u >> 16) & 1u)) >> 16;
    return (short)r;
}
__device__ __forceinline__ float bf2f(short s) {
    union { float f; unsigned u; } v;
    v.u = ((unsigned)(unsigned short)s) << 16;
    return v.f;
}

__global__ __launch_bounds__(512, 2) void rnn_fused(
    const float* __restrict__ x,     // [4096][512][15]
    const float* __restrict__ W_ih,  // [64][15]
    const float* __restrict__ W_hh,  // [64][64]
    const float* __restrict__ b_ih,  // [64]
    const float* __restrict__ b_hh,  // [64]
    const float* __restrict__ fc_w,  // [1][64]
    const float* __restrict__ fc_b,  // [1]
    float* __restrict__ out)         // [4096]
{
    __shared__ __align__(16) short Ahi[2][BPB][ROWSH];
    __shared__ __align__(16) short Alo[2][BPB][ROWSH];

    const int tid  = threadIdx.x;
    const int wave = tid >> 6;        // 0..7, owns j in [8w, 8w+8)
    const int lane = tid & 63;
    const int q    = lane >> 4;
    const int n    = lane & 15;       // batch col on C/D; W col (j=8w+n) on A
    const int b0   = blockIdx.x * BPB;
    const int key  = n & 7;           // XOR swizzle key per LDS row

    // zero LDS: h0 = 0, and pad chunks (logical 10..15) stay zero forever
    for (int idx = tid; idx < 2 * BPB * ROWSH; idx += 512) {
        ((short*)Ahi)[idx] = 0;
        ((short*)Alo)[idx] = 0;
    }

    // --- A-operand fragments: Waug[k][j=8w+n] (zero for n>=8), k=32c+8q+e ---
    short8 whi[3], wlo[2];
    for (int c = 0; c < 3; c++) {
        for (int e = 0; e < 8; e++) {
            int k = c * 32 + q * 8 + e;
            int jcol = 8 * wave + n;
            float w = 0.f;
            if (n < 8) {
                if (k < 64)       w = W_hh[jcol * 64 + k];
                else if (k < 79)  w = W_ih[jcol * 15 + (k - 64)];
            }
            short hi = f2bf_rne(w);
            whi[c][e] = hi;
            if (c < 2) wlo[c][e] = f2bf_rne(w - bf2f(hi));
        }
    }
    // bias per OUTPUT row r: j = 8w + 4q + r (only q<2 rows are real)
    float bias_r[4];
    #pragma unroll
    for (int r = 0; r < 4; r++) {
        int jj = 8 * wave + 4 * q + r;
        if (jj > 63) jj = 63;   // clamp for pad lanes (result discarded)
        bias_r[r] = b_ih[jj] + b_hh[jj];
    }

    // precomputed swizzled LDS addresses (loop-invariant)
    // reads: logical chunk Lc = 4c + q  -> phys = Lc ^ key
    const short* rdh[2][3];
    const short* rdl[2][2];
    for (int pp = 0; pp < 2; pp++) {
        for (int c = 0; c < 3; c++)
            rdh[pp][c] = &Ahi[pp][n][((4 * c + q) ^ key) * 8];
        for (int c = 0; c < 2; c++)
            rdl[pp][c] = &Alo[pp][n][((4 * c + q) ^ key) * 8];
    }
    // h-writes (q<2): logical chunk = wave, intra-offset 4q shorts
    short* wrh[2];
    short* wrl[2];
    for (int pp = 0; pp < 2; pp++) {
        wrh[pp] = &Ahi[pp][n][(wave ^ key) * 8 + 4 * q];
        wrl[pp] = &Alo[pp][n][(wave ^ key) * 8 + 4 * q];
    }

    // x staging: 128 pair-roles on tid<128: batch ns = tid>>3, pair m = tid&7
    // pair m holds (x[2m], x[2m+1]) except m=7 -> (x[14], 0)
    const int ns = tid >> 3, m = tid & 7;
    const bool xactive = tid < 128;
    const bool m7 = (m == 7);
    const float* xrow = x + (size_t)(b0 + ns) * T_STEPS * I_DIM + (m7 ? 14 : 2 * m);
    // x write address: logical chunk 8+(m>>2), intra-offset 2*(m&3) shorts
    short* wrx[2];
    for (int pp = 0; pp < 2; pp++)
        wrx[pp] = &Ahi[pp][ns][((8 + (m >> 2)) ^ (ns & 7)) * 8 + 2 * (m & 3)];

    __syncthreads();   // zero-init visible to all waves

    float2 xv[DPF];
    if (xactive) {
        // x(0) directly into buf 0
        float2 v0;
        v0.x = xrow[0];
        v0.y = m7 ? 0.f : xrow[1];
        unsigned pk0 = (unsigned)(unsigned short)f2bf_rne(v0.x) |
                       ((unsigned)(unsigned short)f2bf_rne(v0.y) << 16);
        *(unsigned*)wrx[0] = pk0;
        #pragma unroll
        for (int d = 1; d <= DPF; d++) {
            const float* px = xrow + (size_t)d * I_DIM;
            float2 v;
            v.x = px[0];
            v.y = m7 ? 0.f : px[1];
            xv[d & (DPF - 1)] = v;
        }
    }
    asm volatile("s_waitcnt lgkmcnt(0)\n\ts_barrier" ::: "memory");

    for (int tb = 0; tb < T_STEPS / DPF; tb++) {
        #pragma unroll
        for (int u = 0; u < DPF; u++) {
            const int t  = tb * DPF + u;
            const int p  = u & 1, pn = p ^ 1;

            // B-operand fragments: h rows (hi+lo) + x chunk
            short8 hhi0 = *(const short8*)rdh[p][0];
            short8 hhi1 = *(const short8*)rdh[p][1];
            short8 hhi2 = *(const short8*)rdh[p][2];
            short8 hlo0 = *(const short8*)rdl[p][0];
            short8 hlo1 = *(const short8*)rdl[p][1];

            // stage x(t+1) into other buffer; refill pipeline slot
            if (xactive) {
                float2 v = xv[(u + 1) & (DPF - 1)];
                unsigned pk = (unsigned)(unsigned short)f2bf_rne(v.x) |
                              ((unsigned)(unsigned short)f2bf_rne(v.y) << 16);
                *(unsigned*)wrx[pn] = pk;
                int tload = t + 1 + DPF;
                if (tload > T_STEPS - 1) tload = T_STEPS - 1;
                const float* px = xrow + (size_t)tload * I_DIM;
                float2 nv;
                nv.x = px[0];
                nv.y = m7 ? 0.f : px[1];
                xv[(u + 1) & (DPF - 1)] = nv;
            }

            // 3 independent chains: Whi*hhi (3), Whi*hlo (2), Wlo*hhi (2)
            float4v acc0 = {0.f, 0.f, 0.f, 0.f};
            float4v acc1 = {0.f, 0.f, 0.f, 0.f};
            float4v acc2 = {0.f, 0.f, 0.f, 0.f};
            acc0 = __builtin_amdgcn_mfma_f32_16x16x32_bf16(whi[0], hhi0, acc0, 0, 0, 0);
            acc1 = __builtin_amdgcn_mfma_f32_16x16x32_bf16(whi[0], hlo0, acc1, 0, 0, 0);
            acc2 = __builtin_amdgcn_mfma_f32_16x16x32_bf16(wlo[0], hhi0, acc2, 0, 0, 0);
            acc0 = __builtin_amdgcn_mfma_f32_16x16x32_bf16(whi[1], hhi1, acc0, 0, 0, 0);
            acc1 = __builtin_amdgcn_mfma_f32_16x16x32_bf16(whi[1], hlo1, acc1, 0, 0, 0);
            acc2 = __builtin_amdgcn_mfma_f32_16x16x32_bf16(wlo[1], hhi1, acc2, 0, 0, 0);
            acc0 = __builtin_amdgcn_mfma_f32_16x16x32_bf16(whi[2], hhi2, acc0, 0, 0, 0);

            // epilogue: D[row=4q+r -> j=8w+4q+r][col=n -> batch]
            // real rows are q<2 only; others compute but don't write
            unsigned hu[4], lu[4];
            #pragma unroll
            for (int r = 0; r < 4; r++) {
                float pre = (acc0[r] + acc1[r]) + (acc2[r] + bias_r[r]);
                float e = __builtin_exp2f(pre * 2.8853900817779268f);
                float h = 1.f - 2.f * __builtin_amdgcn_rcpf(e + 1.f);
                union { float f; unsigned u; } hv; hv.f = h;
                hu[r] = hv.u;
                union { float f; unsigned u; } hb; hb.u = hv.u & 0xFFFF0000u;
                union { float f; unsigned u; } rv; rv.f = h - hb.f;
                lu[r] = rv.u;
            }
            if (q < 2) {
                uint2 hiv, lov;
                hiv.x = (hu[0] >> 16) | (hu[1] & 0xFFFF0000u);
                hiv.y = (hu[2] >> 16) | (hu[3] & 0xFFFF0000u);
                lov.x = (lu[0] >> 16) | (lu[1] & 0xFFFF0000u);
                lov.y = (lu[2] >> 16) | (lu[3] & 0xFFFF0000u);
                *(uint2*)wrh[pn] = hiv;
                *(uint2*)wrl[pn] = lov;
            }

            asm volatile("s_waitcnt lgkmcnt(0)\n\ts_barrier" ::: "memory");
        }
    }

    // final head: h(511) lives in buf 0; last in-loop barrier made it visible
    if (tid < BPB) {
        const int hkey = tid & 7;
        float s = fc_b[0];
        for (int k = 0; k < 64; k++) {
            int idx = ((k >> 3) ^ hkey) * 8 + (k & 7);
            float hv = bf2f(Ahi[0][tid][idx]) + bf2f(Alo[0][tid][idx]);
            s += hv * fc_w[k];
        }
        out[b0 + tid] = s;
    }
}

extern "C" void kernel_launch(void* const* d_in, const int* in_sizes, int n_in,
                              void* d_out, int out_size, void* d_ws, size_t ws_size,
                              hipStream_t stream) {
    const float* x    = (const float*)d_in[0];
    const float* W_ih = (const float*)d_in[1];
    const float* W_hh = (const float*)d_in[2];
    const float* b_ih = (const float*)d_in[3];
    const float* b_hh = (const float*)d_in[4];
    const float* fc_w = (const float*)d_in[5];
    const float* fc_b = (const float*)d_in[6];
    float* out = (float*)d_out;

    rnn_fused<<<4096 / BPB, 512, 0, stream>>>(x, W_ih, W_hh, b_ih, b_hh, fc_w, fc_b, out);
}

// Round 6
// 382.546 us; speedup vs baseline: 1.0505x; 1.0505x over previous
//
#include <hip/hip_runtime.h>

// RNN: B=4096, T=512, I=15, H=64, O=1
// R5 = R3 structure (256 blocks x 4 waves, 16 batches/block, swapped MFMA:
// preact^T[64j][16b] = Waug^T * A^T, zero redundancy, 1 wave/SIMD) with:
//  - x chunk moved OUT of LDS: each lane loads its MFMA B-fragment of x
//    directly from global (2-step register prefetch). A-side W is zero for
//    k>=79 and q>=2, so pad lanes may hold garbage -- no masking needed.
//    q==1's load order (x[8..11],x[11..14]) is compensated in W-frag init.
//  - LDS holds only h (hi+lo bf16), ROWSH=72: reads are 8-phase optimal
//    b128, writes 4-phase optimal b64 (checked by bank arithmetic).
//  - raw s_barrier (lgkmcnt-only drain): x prefetch stays in flight.

#define T_STEPS 512
#define BPB 16
#define ROWSH 72          // shorts per h row (64 + 8 pad); 144B row, 16B-aligned

typedef __attribute__((ext_vector_type(8))) short short8;
typedef __attribute__((ext_vector_type(4))) float float4v;

__device__ __forceinline__ short f2bf_rne(float f) {
    union { float f; unsigned u; } v; v.f = f;
    unsigned r = (v.u + 0x7FFFu + ((v.u >> 16) & 1u)) >> 16;
    return (short)r;
}
__device__ __forceinline__ float bf2f(short s) {
    union { float f; unsigned u; } v;
    v.u = ((unsigned)(unsigned short)s) << 16;
    return v.f;
}
// pack two f32 -> bf16 pair (round-half-up): 2 adds + 1 v_perm
__device__ __forceinline__ unsigned pk2(float f0, float f1) {
    union { float f; unsigned u; } a, b; a.f = f0; b.f = f1;
    return __builtin_amdgcn_perm(b.u + 0x8000u, a.u + 0x8000u, 0x07060302u);
}

__global__ __launch_bounds__(256) void rnn_fused(
    const float* __restrict__ x,     // [4096][512][15]
    const float* __restrict__ W_ih,  // [64][15]
    const float* __restrict__ W_hh,  // [64][64]
    const float* __restrict__ b_ih,  // [64]
    const float* __restrict__ b_hh,  // [64]
    const float* __restrict__ fc_w,  // [1][64]
    const float* __restrict__ fc_b,  // [1]
    float* __restrict__ out)         // [4096]
{
    __shared__ __align__(16) short Ahi[2][BPB][ROWSH];
    __shared__ __align__(16) short Alo[2][BPB][ROWSH];

    const int tid  = threadIdx.x;
    const int wave = tid >> 6;
    const int lane = tid & 63;
    const int q    = lane >> 4;
    const int n    = lane & 15;       // W col (j=16w+n) on A-frag; batch on C/D
    const int jw   = wave * 16 + n;   // weight column this lane supplies
    const int wj0  = wave * 16 + q * 4;  // first j this lane OUTPUTS
    const int b0   = blockIdx.x * BPB;

    // zero LDS h state (h0 = 0; pad cols 64..71 stay 0)
    for (int idx = tid; idx < 2 * BPB * ROWSH; idx += 256) {
        ((short*)Ahi)[idx] = 0;
        ((short*)Alo)[idx] = 0;
    }

    // --- A-operand fragments: Waug[k][jw], k = 32c + 8q + e ---
    // chunk 2 (x-part) is remapped to match the register x-load order:
    //   q==0: e -> x[e]
    //   q==1: e<4 -> x[8+e]; e==4 -> 0 (x[11] duplicate); e>4 -> x[7+e]
    //   q>=2: all zero (pad K)
    short8 whi[3], wlo[2];
    for (int c = 0; c < 3; c++) {
        for (int e = 0; e < 8; e++) {
            float w = 0.f;
            if (c < 2) {
                int k = c * 32 + q * 8 + e;
                w = W_hh[jw * 64 + k];
            } else {
                int xk = -1;
                if (q == 0) xk = e;
                else if (q == 1) xk = (e < 4) ? (8 + e) : (e == 4 ? -1 : (7 + e));
                if (xk >= 0) w = W_ih[jw * 15 + xk];
            }
            short hi = f2bf_rne(w);
            whi[c][e] = hi;
            if (c < 2) wlo[c][e] = f2bf_rne(w - bf2f(hi));
        }
    }
    // bias per OUTPUT row r (j = wj0 + r)
    float bias_r[4];
    #pragma unroll
    for (int r = 0; r < 4; r++) bias_r[r] = b_ih[wj0 + r] + b_hh[wj0 + r];

    // x base pointers for this lane's B-fragment (batch row n of this block)
    const int offA = (q == 1) ? 8 : 0;    // q>=2 load garbage-for-zero-W: use q0 offsets
    const int offB = (q == 1) ? 11 : 4;
    const float* xpA = x + (size_t)(b0 + n) * T_STEPS * 15 + offA;
    const float* xpB = x + (size_t)(b0 + n) * T_STEPS * 15 + offB;

    // LDS read/write pointers (loop-invariant)
    const short* rdh[2][2];
    const short* rdl[2][2];
    short* wrh[2];
    short* wrl[2];
    for (int pp = 0; pp < 2; pp++) {
        for (int c = 0; c < 2; c++) {
            rdh[pp][c] = &Ahi[pp][n][32 * c + 8 * q];
            rdl[pp][c] = &Alo[pp][n][32 * c + 8 * q];
        }
        wrh[pp] = &Ahi[pp][n][wj0];
        wrl[pp] = &Alo[pp][n][wj0];
    }

    // x register pipeline: xcur = x(0); (pa1,pb1) = x(1); (pa0,pb0) = x(2)
    float4v pa0, pb0, pa1, pb1;
    __builtin_memcpy(&pa1, xpA + 0 * 15, 16);
    __builtin_memcpy(&pb1, xpB + 0 * 15, 16);
    __builtin_memcpy(&pa0, xpA + 1 * 15, 16);
    __builtin_memcpy(&pb0, xpB + 1 * 15, 16);
    short8 xcur;
    {
        union { short8 s; unsigned u[4]; } xb;
        xb.u[0] = pk2(pa1.x, pa1.y); xb.u[1] = pk2(pa1.z, pa1.w);
        xb.u[2] = pk2(pb1.x, pb1.y); xb.u[3] = pk2(pb1.z, pb1.w);
        xcur = xb.s;
    }
    __builtin_memcpy(&pa1, xpA + 1 * 15, 16);   // x(1) again into slot 1
    __builtin_memcpy(&pb1, xpB + 1 * 15, 16);
    __builtin_memcpy(&pa0, xpA + 2 * 15, 16);   // x(2)
    __builtin_memcpy(&pb0, xpB + 2 * 15, 16);

    __syncthreads();   // zeros visible (full barrier once, before the loop)

    for (int t = 0; t < T_STEPS; t += 2) {
        #pragma unroll
        for (int u = 0; u < 2; u++) {
            const int p  = u, pn = u ^ 1;

            // B-operand h fragments (hi + lo)
            short8 hhi0 = *(const short8*)rdh[p][0];
            short8 hhi1 = *(const short8*)rdh[p][1];
            short8 hlo0 = *(const short8*)rdl[p][0];
            short8 hlo1 = *(const short8*)rdl[p][1];

            // 3 independent chains: Whi*hhi + Whi2*x (3), Whi*hlo (2), Wlo*hhi (2)
            float4v acc0 = {0.f, 0.f, 0.f, 0.f};
            float4v acc1 = {0.f, 0.f, 0.f, 0.f};
            float4v acc2 = {0.f, 0.f, 0.f, 0.f};
            acc0 = __builtin_amdgcn_mfma_f32_16x16x32_bf16(whi[0], hhi0, acc0, 0, 0, 0);
            acc1 = __builtin_amdgcn_mfma_f32_16x16x32_bf16(whi[0], hlo0, acc1, 0, 0, 0);
            acc2 = __builtin_amdgcn_mfma_f32_16x16x32_bf16(wlo[0], hhi0, acc2, 0, 0, 0);
            acc0 = __builtin_amdgcn_mfma_f32_16x16x32_bf16(whi[1], hhi1, acc0, 0, 0, 0);
            acc1 = __builtin_amdgcn_mfma_f32_16x16x32_bf16(whi[1], hlo1, acc1, 0, 0, 0);
            acc2 = __builtin_amdgcn_mfma_f32_16x16x32_bf16(wlo[1], hhi1, acc2, 0, 0, 0);
            acc0 = __builtin_amdgcn_mfma_f32_16x16x32_bf16(whi[2], xcur, acc0, 0, 0, 0);

            // rotate x pipeline: xcur <- x(t+u+1); refill slot with x(t+u+3)
            {
                float4v& pa = u ? pa0 : pa1;
                float4v& pb = u ? pb0 : pb1;
                union { short8 s; unsigned uu[4]; } xb;
                xb.uu[0] = pk2(pa.x, pa.y); xb.uu[1] = pk2(pa.z, pa.w);
                xb.uu[2] = pk2(pb.x, pb.y); xb.uu[3] = pk2(pb.z, pb.w);
                int tl = t + u + 3; if (tl > T_STEPS - 1) tl = T_STEPS - 1;
                __builtin_memcpy(&pa, xpA + (size_t)tl * 15, 16);
                __builtin_memcpy(&pb, xpB + (size_t)tl * 15, 16);
                xcur = xb.s;
            }

            // epilogue: D[row=4q+r -> j=wj0+r][col=n -> batch n]
            unsigned hu[4], lu[4];
            #pragma unroll
            for (int r = 0; r < 4; r++) {
                float pre = (acc0[r] + acc1[r]) + (acc2[r] + bias_r[r]);
                float e = __builtin_exp2f(pre * 2.8853900817779268f);
                float h = 1.f - 2.f * __builtin_amdgcn_rcpf(e + 1.f);
                union { float f; unsigned u; } hv; hv.f = h;
                hu[r] = hv.u;
                union { float f; unsigned u; } hb; hb.u = hv.u & 0xFFFF0000u;
                union { float f; unsigned u; } rv; rv.f = h - hb.f;
                lu[r] = rv.u;
            }
            uint2 hiv, lov;
            hiv.x = (hu[0] >> 16) | (hu[1] & 0xFFFF0000u);
            hiv.y = (hu[2] >> 16) | (hu[3] & 0xFFFF0000u);
            lov.x = (lu[0] >> 16) | (lu[1] & 0xFFFF0000u);
            lov.y = (lu[2] >> 16) | (lu[3] & 0xFFFF0000u);
            *(uint2*)wrh[pn] = hiv;
            *(uint2*)wrl[pn] = lov;

            // raw barrier: drain LDS only; x global prefetch stays in flight
            asm volatile("s_waitcnt lgkmcnt(0)\n\ts_barrier" ::: "memory");
        }
    }

    // final head: h(511) lives in buf 0 (T even); last barrier made it visible
    if (tid < BPB) {
        float s = fc_b[0];
        for (int k = 0; k < 64; k++) {
            float hv = bf2f(Ahi[0][tid][k]) + bf2f(Alo[0][tid][k]);
            s += hv * fc_w[k];
        }
        out[b0 + tid] = s;
    }
}

extern "C" void kernel_launch(void* const* d_in, const int* in_sizes, int n_in,
                              void* d_out, int out_size, void* d_ws, size_t ws_size,
                              hipStream_t stream) {
    const float* x    = (const float*)d_in[0];
    const float* W_ih = (const float*)d_in[1];
    const float* W_hh = (const float*)d_in[2];
    const float* b_ih = (const float*)d_in[3];
    const float* b_hh = (const float*)d_in[4];
    const float* fc_w = (const float*)d_in[5];
    const float* fc_b = (const float*)d_in[6];
    float* out = (float*)d_out;

    rnn_fused<<<4096 / BPB, 256, 0, stream>>>(x, W_ih, W_hh, b_ih, b_hh, fc_w, fc_b, out);
}